// Round 1
// 1663.184 us; speedup vs baseline: 1.4716x; 1.4716x over previous
//
#include <hip/hip_runtime.h>
#include <cstdint>
#include <cstddef>

// ---- problem constants ----
#define BB 64
#define PE 196      // P
#define PP 208      // padded P (multiple of 16)
#define ENC 2048
#define LL 20
#define TT 19       // T = L-1
#define VV 32000
#define HH 512
#define AA 512
#define KCAT 3072   // E + ENC + H   (x_cat = [emb | ctx | h])
#define XROW 3072
#define MROW 1216   // BB*TT rows of hsave actually used
#define MPAD 1280   // padded to 10 x 128 tiles

typedef __attribute__((ext_vector_type(8))) short bf16x8;
typedef __attribute__((ext_vector_type(4))) float f32x4;
typedef unsigned short u16;
typedef unsigned int u32;

__device__ __forceinline__ float bf2f(u16 s){ return __uint_as_float(((u32)s) << 16); }
__device__ __forceinline__ u16 f2bf(float f){
  u32 u = __float_as_uint(f);
  u32 r = (u + 0x7FFFu + ((u >> 16) & 1u)) >> 16;
  return (u16)r;
}
__device__ __forceinline__ f32x4 mfma16(bf16x8 a, bf16x8 b, f32x4 c){
  return __builtin_amdgcn_mfma_f32_16x16x32_bf16(a, b, c, 0, 0, 0);
}
__device__ __forceinline__ float sigm(float x){ return 1.f / (1.f + __expf(-x)); }

__device__ __forceinline__ void gl_lds16(const u16* g, u16* l){
  __builtin_amdgcn_global_load_lds(
      (const __attribute__((address_space(1))) void*)g,
      (__attribute__((address_space(3))) void*)l, 16, 0, 0);
}

// ---------- setup kernels ----------

__global__ void k_sort(const int* __restrict__ y, int* __restrict__ sidx, int* __restrict__ dlen,
                       float* __restrict__ out_dlen, float* __restrict__ out_sidx){
  __shared__ int cl[BB];
  int b = threadIdx.x;
  int c = 0;
  for (int l = 0; l < LL; l++) c += (y[b*LL + l] != 0);
  cl[b] = c;
  __syncthreads();
  int r = 0;
  for (int j = 0; j < BB; j++){
    int cj = cl[j];
    r += (cj > c) || (cj == c && j < b);
  }
  sidx[r] = b; dlen[r] = c - 1;
  out_sidx[r] = (float)b; out_dlen[r] = (float)(c - 1);
}

__global__ void k_cvt(u16* __restrict__ dst, const float* __restrict__ src, int n){
  int i = blockIdx.x * blockDim.x + threadIdx.x;
  int stride = gridDim.x * blockDim.x;
  for (; i < n; i += stride) dst[i] = f2bf(src[i]);
}

__global__ void k_wcat(u16* __restrict__ wcat, const float* __restrict__ wih, const float* __restrict__ whh){
  int r = blockIdx.x;
  for (int j = threadIdx.x; j < KCAT; j += 256){
    float v = (j < 2560) ? wih[(size_t)r*2560 + j] : whh[(size_t)r*HH + (j - 2560)];
    wcat[(size_t)r*KCAT + j] = f2bf(v);
  }
}

__global__ void k_gather(u16* __restrict__ encb, const float* __restrict__ enc, const int* __restrict__ sidx){
  int b = blockIdx.x, pg = blockIdx.y;
  int s = sidx[b];
  const float* src = enc + (size_t)s * PE * ENC;
  u16* dst = encb + ((size_t)b * PP + pg * 8) * ENC;
  for (int i = threadIdx.x; i < 8 * ENC; i += 256){
    int p = pg * 8 + (i >> 11);
    dst[i] = (p < PE) ? f2bf(src[(size_t)p * ENC + (i & 2047)]) : (u16)0;
  }
}

// grid (64,8): one e per thread, 196 strided loads with deep unroll
__global__ void k_mean(float* __restrict__ mean, const u16* __restrict__ encb){
  int b = blockIdx.x;
  int e = blockIdx.y * 256 + threadIdx.x;
  const u16* p = encb + (size_t)b * PP * ENC + e;
  float s = 0.f;
#pragma unroll 14
  for (int pp = 0; pp < PE; pp++) s += bf2f(p[(size_t)pp * ENC]);
  mean[b*ENC + e] = s * (1.0f / 196.0f);
}

__global__ void k_embed(u16* __restrict__ embb, const float* __restrict__ table,
                        const int* __restrict__ y, const int* __restrict__ sidx){
  int b = blockIdx.x; int s = sidx[b];
  for (int i = threadIdx.x; i < TT * HH; i += 256){
    int tt = i >> 9, j = i & 511;
    int tok = y[s*LL + tt];
    embb[((size_t)b*TT + tt)*HH + j] = f2bf(table[(size_t)tok * HH + j]);
  }
}

// h0 (bf16 into x_cat h-slot) and c0 (fp32), float4-vectorized K loop
__global__ void k_init(u16* __restrict__ xcat, float* __restrict__ cws, const float* __restrict__ mean,
                       const float* __restrict__ hW, const float* __restrict__ hb,
                       const float* __restrict__ cW, const float* __restrict__ cb){
  int isC = blockIdx.y;
  int col = blockIdx.x * 4 + (threadIdx.x >> 6);
  int row = threadIdx.x & 63;
  const float* W = isC ? cW : hW;
  const float4* m4 = (const float4*)(mean + (size_t)row * ENC);
  const float4* w4 = (const float4*)(W + (size_t)col * ENC);
  float acc = 0.f;
#pragma unroll 8
  for (int k = 0; k < ENC/4; k++){
    float4 a = m4[k], w = w4[k];
    acc = fmaf(a.x, w.x, acc); acc = fmaf(a.y, w.y, acc);
    acc = fmaf(a.z, w.z, acc); acc = fmaf(a.w, w.w, acc);
  }
  if (isC) cws[row*HH + col] = acc + cb[col];
  else     xcat[(size_t)row*XROW + 2560 + col] = f2bf(acc + hb[col]);
}

// att1[b][p][a]: m97-style 128x128 LDS-tiled MFMA GEMM, M = BB*PP = 13312, N = 512, K = 2048
__global__ __launch_bounds__(256, 2) void k_att1(u16* __restrict__ att1,
                                                 const u16* __restrict__ encb,
                                                 const u16* __restrict__ e2a){
  __shared__ u16 ldsA[128 * 32];
  __shared__ u16 ldsB[128 * 32];
  int tid = threadIdx.x;
  int wave = tid >> 6, lane = tid & 63, quad = lane >> 4, l15 = lane & 15, kq = quad * 8;
  int mbase = blockIdx.x * 128;
  int nbase = blockIdx.y * 128;
  int wm = (wave >> 1) * 64, wn = (wave & 1) * 64;

  int srow = tid >> 2;
  int scol = (tid & 3) * 8;
  const u16* gA0 = encb + (size_t)(mbase + srow) * ENC + scol;
  const u16* gA1 = encb + (size_t)(mbase + 64 + srow) * ENC + scol;
  const u16* gB0 = e2a  + (size_t)(nbase + srow) * ENC + scol;
  const u16* gB1 = e2a  + (size_t)(nbase + 64 + srow) * ENC + scol;
  u16* lA0 = ldsA + tid * 8;
  u16* lA1 = ldsA + 2048 + tid * 8;
  u16* lB0 = ldsB + tid * 8;
  u16* lB1 = ldsB + 2048 + tid * 8;

  f32x4 acc[4][4] = {};
  for (int k0 = 0; k0 < ENC; k0 += 32){
    gl_lds16(gA0 + k0, lA0);
    gl_lds16(gA1 + k0, lA1);
    gl_lds16(gB0 + k0, lB0);
    gl_lds16(gB1 + k0, lB1);
    __syncthreads();
    bf16x8 af[4], bfr[4];
#pragma unroll
    for (int i = 0; i < 4; i++) af[i]  = *(const bf16x8*)(ldsA + (wm + i*16 + l15) * 32 + kq);
#pragma unroll
    for (int j = 0; j < 4; j++) bfr[j] = *(const bf16x8*)(ldsB + (wn + j*16 + l15) * 32 + kq);
#pragma unroll
    for (int i = 0; i < 4; i++)
#pragma unroll
      for (int j = 0; j < 4; j++)
        acc[i][j] = mfma16(af[i], bfr[j], acc[i][j]);
    __syncthreads();
  }
#pragma unroll
  for (int i = 0; i < 4; i++)
#pragma unroll
    for (int j = 0; j < 4; j++)
#pragma unroll
      for (int r = 0; r < 4; r++){
        int m = mbase + wm + i*16 + quad*4 + r;
        int n = nbase + wn + j*16 + l15;
        att1[(size_t)m * AA + n] = f2bf(acc[i][j][r]);
      }
}

// ---------- per-step kernels ----------

// att2cat = h @ [h2a|f_beta]^T (N=2560, K=512); 1 wave/block, grid 160 for CU spread
__global__ void k_hmat(float* __restrict__ att2, float* __restrict__ gatelin,
                       const u16* __restrict__ xcat, const u16* __restrict__ whcat){
  int lane = threadIdx.x, quad = lane >> 4, l15 = lane & 15, kq = quad * 8;
  int n = blockIdx.x * 16 + l15;   // 0..2559
  const u16* bp = whcat + (size_t)n * HH + kq;
  f32x4 acc[4] = {};
#pragma unroll 4
  for (int k0 = 0; k0 < HH; k0 += 32){
    bf16x8 bv = *(const bf16x8*)(bp + k0);
#pragma unroll
    for (int mt = 0; mt < 4; mt++){
      bf16x8 av = *(const bf16x8*)(xcat + (size_t)(mt*16 + l15)*XROW + 2560 + kq + k0);
      acc[mt] = mfma16(av, bv, acc[mt]);
    }
  }
#pragma unroll
  for (int mt = 0; mt < 4; mt++)
#pragma unroll
    for (int r = 0; r < 4; r++){
      int m = mt*16 + quad*4 + r;
      float v = acc[mt][r];
      if (n < HH) att2[m*HH + n] = v;
      else        gatelin[m*ENC + (n - HH)] = v;
    }
}

// score + softmax + alpha write (block per batch row); att1 layout [b][p][a] -> contiguous reads
__global__ void k_score(float* __restrict__ out_alph, float* __restrict__ alpha_ws,
                        const u16* __restrict__ att1, const float* __restrict__ att2,
                        const float* __restrict__ attW, const float* __restrict__ attb,
                        const int* __restrict__ dlen, int t){
  __shared__ float a2s[AA], aws[AA], red[256];
  int b = blockIdx.x, tid = threadIdx.x;
  float* oa = out_alph + ((size_t)b*TT + t) * PE;
  if (dlen[b] <= t){
    if (tid < PE) oa[tid] = 0.f;
    return;
  }
  a2s[tid] = att2[b*AA + tid]; a2s[tid+256] = att2[b*AA + tid + 256];
  aws[tid] = attW[tid];        aws[tid+256] = attW[tid + 256];
  __syncthreads();
  float sc = -3.4e38f;
  if (tid < PE){
    const u16* row = att1 + ((size_t)b*PP + tid) * AA;
    float acc = 0.f;
#pragma unroll 8
    for (int a0 = 0; a0 < AA; a0 += 8){
      bf16x8 v = *(const bf16x8*)(row + a0);
#pragma unroll
      for (int j = 0; j < 8; j++){
        float x = bf2f((u16)v[j]) + a2s[a0 + j];
        acc = fmaf(fmaxf(x, 0.f), aws[a0 + j], acc);
      }
    }
    sc = acc + attb[0];
  }
  red[tid] = sc; __syncthreads();
  for (int s = 128; s > 0; s >>= 1){ if (tid < s) red[tid] = fmaxf(red[tid], red[tid+s]); __syncthreads(); }
  float mx = red[0]; __syncthreads();
  float ex = (tid < PE) ? __expf(sc - mx) : 0.f;
  red[tid] = ex; __syncthreads();
  for (int s = 128; s > 0; s >>= 1){ if (tid < s) red[tid] += red[tid+s]; __syncthreads(); }
  float inv = 1.f / red[0];
  if (tid < PE) oa[tid] = ex * inv;
  if (tid < PP) alpha_ws[b*PP + tid] = (tid < PE) ? ex * inv : 0.f;
}

// context + gate -> x_cat ctx slot; block.y==0 also copies emb slot
__global__ void k_ctx(u16* __restrict__ xcat, const u16* __restrict__ encb,
                      const float* __restrict__ alpha_ws, const float* __restrict__ gatelin,
                      const float* __restrict__ fbb, const u16* __restrict__ embb,
                      const int* __restrict__ dlen, int t){
  int b = blockIdx.x;
  if (dlen[b] <= t) return;
  __shared__ float al[PP];
  int tid = threadIdx.x;
  if (tid < PP) al[tid] = alpha_ws[b*PP + tid];
  __syncthreads();
  int e = blockIdx.y * 256 + tid;
  const u16* ep = encb + (size_t)b*PP*ENC + e;
  float acc = 0.f;
#pragma unroll 14
  for (int p = 0; p < PE; p++) acc = fmaf(al[p], bf2f(ep[(size_t)p * ENC]), acc);
  float g = sigm(gatelin[b*ENC + e] + fbb[e]);
  xcat[(size_t)b*XROW + 512 + e] = f2bf(g * acc);
  if (blockIdx.y == 0){
    for (int j = tid; j < 512; j += 256)
      xcat[(size_t)b*XROW + j] = embb[((size_t)b*TT + t)*HH + j];
  }
}

// gates GEMM (K=3072, quadrants i/f/g/o co-resident per lane) + fused LSTM pointwise.
// Split-K x4: 4 waves each cover 768 of K (24 iters), partials reduced via LDS,
// wave 0 runs the pointwise epilogue. Also records h_t into hsave for the
// batched end-of-loop FC GEMM.
__global__ void k_gates(u16* __restrict__ xcat, float* __restrict__ cws,
                        u16* __restrict__ hsave,
                        const u16* __restrict__ wcat,
                        const float* __restrict__ bih, const float* __restrict__ bhh,
                        const int* __restrict__ dlen, int t){
  __shared__ float red[4][16][64];   // [wave][gate*4+r][lane] - lane-contiguous, conflict-free
  int tid = threadIdx.x;
  int wave = tid >> 6, lane = tid & 63, quad = lane >> 4, l15 = lane & 15, kq = quad * 8;
  int col = blockIdx.x*16 + l15;    // 0..511 within quadrant
  int mb = blockIdx.y * 16;         // m-tile base
  int kbase = wave * 768;           // split-K chunk
  const u16* ap = xcat + (size_t)(mb + l15)*XROW + kbase + kq;
  const u16* b0p = wcat + (size_t)(col)       *KCAT + kbase + kq;
  const u16* b1p = wcat + (size_t)(512 + col) *KCAT + kbase + kq;
  const u16* b2p = wcat + (size_t)(1024 + col)*KCAT + kbase + kq;
  const u16* b3p = wcat + (size_t)(1536 + col)*KCAT + kbase + kq;
  f32x4 a0 = {}, a1 = {}, a2 = {}, a3 = {};
#pragma unroll 4
  for (int k0 = 0; k0 < 768; k0 += 32){
    bf16x8 a  = *(const bf16x8*)(ap + k0);
    bf16x8 b0 = *(const bf16x8*)(b0p + k0);
    bf16x8 b1 = *(const bf16x8*)(b1p + k0);
    bf16x8 b2 = *(const bf16x8*)(b2p + k0);
    bf16x8 b3 = *(const bf16x8*)(b3p + k0);
    a0 = mfma16(a, b0, a0); a1 = mfma16(a, b1, a1);
    a2 = mfma16(a, b2, a2); a3 = mfma16(a, b3, a3);
  }
#pragma unroll
  for (int r = 0; r < 4; r++){
    red[wave][r][lane]      = a0[r];
    red[wave][4 + r][lane]  = a1[r];
    red[wave][8 + r][lane]  = a2[r];
    red[wave][12 + r][lane] = a3[r];
  }
  __syncthreads();
  if (wave == 0){
    float g0[4], g1[4], g2[4], g3[4];
#pragma unroll
    for (int r = 0; r < 4; r++){
      g0[r] = red[0][r][lane]      + red[1][r][lane]      + red[2][r][lane]      + red[3][r][lane];
      g1[r] = red[0][4+r][lane]    + red[1][4+r][lane]    + red[2][4+r][lane]    + red[3][4+r][lane];
      g2[r] = red[0][8+r][lane]    + red[1][8+r][lane]    + red[2][8+r][lane]    + red[3][8+r][lane];
      g3[r] = red[0][12+r][lane]   + red[1][12+r][lane]   + red[2][12+r][lane]   + red[3][12+r][lane];
    }
    float bi0 = bih[col]      + bhh[col];
    float bi1 = bih[512+col]  + bhh[512+col];
    float bi2 = bih[1024+col] + bhh[1024+col];
    float bi3 = bih[1536+col] + bhh[1536+col];
#pragma unroll
    for (int r = 0; r < 4; r++){
      int m = mb + quad*4 + r;
      if (dlen[m] > t){
        float gi = g0[r] + bi0, gf = g1[r] + bi1, gg = g2[r] + bi2, go = g3[r] + bi3;
        float cn = sigm(gf) * cws[m*HH + col] + sigm(gi) * tanhf(gg);
        cws[m*HH + col] = cn;
        u16 hb = f2bf(sigm(go) * tanhf(cn));
        xcat[(size_t)m*XROW + 2560 + col] = hb;
        hsave[((size_t)m*TT + t)*HH + col] = hb;
      }
    }
  }
}

// Batched FC: logits for ALL (b,t) in one 128x128-tiled MFMA GEMM.
// M = 1216 rows of hsave (padded 1280), N = 32000, K = 512.
// Inactive (b,t) rows contain garbage in hsave; MFMA rows are independent,
// so they are simply masked to 0 at the store (matches reference preds_t=0).
__global__ __launch_bounds__(256, 2) void k_fcall(float* __restrict__ out,
                                                  const u16* __restrict__ hsave,
                                                  const u16* __restrict__ fcw,
                                                  const float* __restrict__ fcb,
                                                  const int* __restrict__ dlen){
  __shared__ u16 ldsA[128 * 32];
  __shared__ u16 ldsB[128 * 32];
  int tid = threadIdx.x;
  int wave = tid >> 6, lane = tid & 63, quad = lane >> 4, l15 = lane & 15, kq = quad * 8;
  int mbase = blockIdx.x * 128;
  int nbase = blockIdx.y * 128;
  int wm = (wave >> 1) * 64, wn = (wave & 1) * 64;

  int srow = tid >> 2;
  int scol = (tid & 3) * 8;
  const u16* gA0 = hsave + (size_t)(mbase + srow) * HH + scol;
  const u16* gA1 = hsave + (size_t)(mbase + 64 + srow) * HH + scol;
  const u16* gB0 = fcw + (size_t)(nbase + srow) * HH + scol;
  const u16* gB1 = fcw + (size_t)(nbase + 64 + srow) * HH + scol;
  u16* lA0 = ldsA + tid * 8;
  u16* lA1 = ldsA + 2048 + tid * 8;
  u16* lB0 = ldsB + tid * 8;
  u16* lB1 = ldsB + 2048 + tid * 8;

  f32x4 acc[4][4] = {};
  for (int k0 = 0; k0 < HH; k0 += 32){
    gl_lds16(gA0 + k0, lA0);
    gl_lds16(gA1 + k0, lA1);
    gl_lds16(gB0 + k0, lB0);
    gl_lds16(gB1 + k0, lB1);
    __syncthreads();
    bf16x8 af[4], bfr[4];
#pragma unroll
    for (int i = 0; i < 4; i++) af[i]  = *(const bf16x8*)(ldsA + (wm + i*16 + l15) * 32 + kq);
#pragma unroll
    for (int j = 0; j < 4; j++) bfr[j] = *(const bf16x8*)(ldsB + (wn + j*16 + l15) * 32 + kq);
#pragma unroll
    for (int i = 0; i < 4; i++)
#pragma unroll
      for (int j = 0; j < 4; j++)
        acc[i][j] = mfma16(af[i], bfr[j], acc[i][j]);
    __syncthreads();
  }
#pragma unroll
  for (int i = 0; i < 4; i++)
#pragma unroll
    for (int r = 0; r < 4; r++){
      int m = mbase + wm + i*16 + quad*4 + r;   // GEMM row = b*TT + t
      if (m < MROW){
        int b = m / TT, t = m - b*TT;
        bool act = dlen[b] > t;
        float* op = out + (size_t)m * VV + nbase + wn + l15;
#pragma unroll
        for (int j = 0; j < 4; j++){
          int n = nbase + wn + j*16 + l15;
          op[j*16] = act ? (acc[i][j][r] + fcb[n]) : 0.f;
        }
      }
    }
}

// ---------- launcher ----------
extern "C" void kernel_launch(void* const* d_in, const int* in_sizes, int n_in,
                              void* d_out, int out_size, void* d_ws, size_t ws_size,
                              hipStream_t stream){
  const float* enc  = (const float*)d_in[0];
  const int*   y    = (const int*)  d_in[1];
  const float* etab = (const float*)d_in[2];
  const float* e2aW = (const float*)d_in[3];
  const float* h2aW = (const float*)d_in[4];
  const float* attW = (const float*)d_in[5];
  const float* attb = (const float*)d_in[6];
  const float* fbW  = (const float*)d_in[7];
  const float* fbb  = (const float*)d_in[8];
  const float* wih  = (const float*)d_in[9];
  const float* bih  = (const float*)d_in[10];
  const float* whh  = (const float*)d_in[11];
  const float* bhh  = (const float*)d_in[12];
  const float* fcW  = (const float*)d_in[13];
  const float* fcb  = (const float*)d_in[14];
  const float* ihW  = (const float*)d_in[15];
  const float* ihb  = (const float*)d_in[16];
  const float* icW  = (const float*)d_in[17];
  const float* icb  = (const float*)d_in[18];

  char* ws = (char*)d_ws;
  size_t off = 0;
  auto alloc = [&](size_t bytes){ void* p = ws + off; off += (bytes + 255) & ~(size_t)255; return p; };
  u16* encb    = (u16*)alloc((size_t)BB*PP*ENC*2);
  u16* att1    = (u16*)alloc((size_t)BB*PP*AA*2);
  u16* fcwb    = (u16*)alloc((size_t)VV*HH*2);
  u16* wcat    = (u16*)alloc((size_t)2048*KCAT*2);
  u16* whcat   = (u16*)alloc((size_t)2560*HH*2);
  u16* e2ab    = (u16*)alloc((size_t)AA*ENC*2);
  u16* embb    = (u16*)alloc((size_t)BB*TT*HH*2);
  u16* xcat    = (u16*)alloc((size_t)BB*XROW*2);
  u16* hsave   = (u16*)alloc((size_t)MPAD*HH*2);
  float* att2  = (float*)alloc((size_t)BB*AA*4);
  float* gatel = (float*)alloc((size_t)BB*ENC*4);
  float* alphw = (float*)alloc((size_t)BB*PP*4);
  float* cws   = (float*)alloc((size_t)BB*HH*4);
  float* mean  = (float*)alloc((size_t)BB*ENC*4);
  int* sidx    = (int*)alloc(BB*4);
  int* dlen    = (int*)alloc(BB*4);

  float* out      = (float*)d_out;
  float* out_alph = out + (size_t)BB*TT*VV;
  float* out_dlen = out_alph + (size_t)BB*TT*PE;
  float* out_sidx = out_dlen + BB;

  k_sort<<<1, 64, 0, stream>>>(y, sidx, dlen, out_dlen, out_sidx);
  k_cvt<<<2048, 256, 0, stream>>>(e2ab, e2aW, AA*ENC);
  k_cvt<<<2048, 256, 0, stream>>>(whcat, h2aW, AA*HH);
  k_cvt<<<2048, 256, 0, stream>>>(whcat + (size_t)AA*HH, fbW, ENC*HH);
  k_cvt<<<2048, 256, 0, stream>>>(fcwb, fcW, VV*HH);
  k_wcat<<<2048, 256, 0, stream>>>(wcat, wih, whh);
  k_gather<<<dim3(64, 26), 256, 0, stream>>>(encb, enc, sidx);
  k_mean<<<dim3(64, 8), 256, 0, stream>>>(mean, encb);
  k_embed<<<64, 256, 0, stream>>>(embb, etab, y, sidx);
  k_init<<<dim3(128, 2), 256, 0, stream>>>(xcat, cws, mean, ihW, ihb, icW, icb);
  k_att1<<<dim3(104, 4), 256, 0, stream>>>(att1, encb, e2ab);

  for (int t = 0; t < TT; t++){
    k_hmat<<<160, 64, 0, stream>>>(att2, gatel, xcat, whcat);
    k_score<<<64, 256, 0, stream>>>(out_alph, alphw, att1, att2, attW, attb, dlen, t);
    k_ctx<<<dim3(64, 8), 256, 0, stream>>>(xcat, encb, alphw, gatel, fbb, embb, dlen, t);
    k_gates<<<dim3(32, 4), 256, 0, stream>>>(xcat, cws, hsave, wcat, bih, bhh, dlen, t);
  }
  // batched logits GEMM, off the serial critical path
  k_fcall<<<dim3(MPAD/128, VV/128), 256, 0, stream>>>(out, hsave, fcwb, fcb, dlen);
}